// Round 9
// baseline (1557.048 us; speedup 1.0000x reference)
//
#include <hip/hip_runtime.h>
#include <hip/hip_bf16.h>
#include <math.h>

// ---------------------------------------------------------------------------
// ViT forward. Round 5 (4th submit; three GPU-acquisition timeouts): fused MLP
// (mlp1 + GeLU + mlp2 in one kernel, h in LDS).
// B=128, C=3, 224x224, P=14, IN_D=768, D=256, H=8, DH=32, L=4, OUT=1000, S=197
// ---------------------------------------------------------------------------

#define SEQ 197
#define DIM 256
#define NB  128
#define MROWS (NB * SEQ)        // 25216 = 197*128

typedef __attribute__((ext_vector_type(4))) float f32x4;
typedef __attribute__((ext_vector_type(8))) __bf16 bf16x8;
typedef __attribute__((ext_vector_type(8))) short s16x8;

// async global->LDS, 16B per lane; LDS dest must be wave-uniform base
#define GLOAD16(g, l)                                                          \
    __builtin_amdgcn_global_load_lds(                                          \
        (const __attribute__((address_space(1))) void*)(g),                    \
        (__attribute__((address_space(3))) void*)(l), 16, 0, 0)

// round-to-nearest-even fp32 -> bf16 bits
__device__ __forceinline__ unsigned bf16_rn(float x) {
    union { float f; unsigned u; } c; c.f = x;
    return (c.u + 0x7fffu + ((c.u >> 16) & 1u)) >> 16;
}
__device__ __forceinline__ void split2(float a, unsigned short& hi, unsigned short& lo) {
    unsigned h = bf16_rn(a);
    hi = (unsigned short)h;
    union { unsigned u; float f; } hf; hf.u = h << 16;
    lo = (unsigned short)bf16_rn(a - hf.f);
}
// swizzled element offset in a [128 rows][32 k] ushort LDS tile (16B chunks XORed)
__device__ __forceinline__ int swz(int row, int c) {
    return row * 32 + ((c ^ ((row >> 1) & 3)) << 3);
}

// ---------------------------------------------------------------------------
__global__ __launch_bounds__(256) void pe_kernel(float* __restrict__ pe) {
    int s = blockIdx.x, j = threadIdx.x;
    int jh = j >> 1;
    float expo = (float)(2 * jh) * (1.0f / 256.0f);
    float inv_freq = exp2f(-expo * 13.287712379549449f);
    float angle = (float)s * inv_freq;
    pe[s * 256 + j] = (j & 1) ? cosf(angle) : sinf(angle);
}

__global__ __launch_bounds__(256) void embed_cls(const float* __restrict__ cls_tok,
                                                 const float* __restrict__ pe,
                                                 float* __restrict__ out) {
    int n = blockIdx.x, d = threadIdx.x;
    out[(size_t)n * SEQ * DIM + d] = cls_tok[d] + pe[d];
}

// split fp32 weights into hi/lo bf16 copies
__global__ __launch_bounds__(256) void split_weights(const float* __restrict__ src,
                                                     unsigned short* __restrict__ hi,
                                                     unsigned short* __restrict__ lo, int n) {
    for (int i = blockIdx.x * 256 + threadIdx.x; i < n; i += gridDim.x * 256) {
        unsigned short h, l;
        split2(src[i], h, l);
        hi[i] = h; lo[i] = l;
    }
}

// Compact QKV weights: wc[l][j][d] (j = m*256 + hh*32 + e, d = 0..31), hi bf16.
__global__ __launch_bounds__(256) void pack_qkv_c(const float* __restrict__ wq,
                                                  const float* __restrict__ wk,
                                                  const float* __restrict__ wv,
                                                  unsigned short* __restrict__ wc) {
    int e = blockIdx.x * 256 + threadIdx.x;     // < 4*768*32 = 98304
    if (e >= 98304) return;
    int l = e / 24576, r = e % 24576;
    int j = r >> 5, d = r & 31;
    int m = j >> 8, hh = (j >> 5) & 7, ee = j & 31;
    const float* w = (m == 0) ? wq : (m == 1) ? wk : wv;
    wc[e] = (unsigned short)bf16_rn(w[(((size_t)l * 8 + hh) * 32 + ee) * 32 + d]);
}

__global__ __launch_bounds__(256) void pack_qkv_b(const float* __restrict__ bq,
                                                  const float* __restrict__ bk,
                                                  const float* __restrict__ bv,
                                                  float* __restrict__ bp) {
    int e = blockIdx.x * 256 + threadIdx.x;     // < 4*768 = 3072
    if (e >= 3072) return;
    int l = e / 768, j = e % 768;
    int m = j >> 8, jj = j & 255;
    const float* b = (m == 0) ? bq : (m == 1) ? bk : bv;
    bp[e] = b[l * 256 + jj];
}

// ---------------------------------------------------------------------------
// GEMM with pre-split bf16 A and B, async LDS staging. (used for o-proj)
// C[M,N] = act(A * B^T + bias);  OMODE: 0 store f32, 1 accum f32.
template <int ACT, int OMODE, bool ALO>
__global__ __launch_bounds__(256) void gemm_as(const unsigned short* __restrict__ Ahi,
                                               const unsigned short* __restrict__ Alo,
                                               const unsigned short* __restrict__ Bhi,
                                               const unsigned short* __restrict__ Blo,
                                               const float* __restrict__ bias,
                                               float* __restrict__ C,
                                               int M, int N, int K) {
    __shared__ unsigned short Ah[4096], Al[4096], Bh[4096], Bl[4096];
    const int tid = threadIdx.x;
    const int bm = blockIdx.y * 128, bn = blockIdx.x * 128;
    const int lane = tid & 63, wid = tid >> 6;
    const int wm = wid & 1, wn = wid >> 1;
    const int q = lane >> 4, r15 = lane & 15;
    const int rl = lane >> 2, cc = lane & 3;
    const int wr = wid * 32;

    const int row0 = wr + rl, row1 = wr + 16 + rl;
    const int cx0 = (cc ^ ((row0 >> 1) & 3)) << 3;
    const int cx1 = (cc ^ ((row1 >> 1) & 3)) << 3;
    const unsigned short* ah0 = Ahi + (size_t)(bm + row0) * K + cx0;
    const unsigned short* ah1 = Ahi + (size_t)(bm + row1) * K + cx1;
    const unsigned short* al0 = Alo + (size_t)(bm + row0) * K + cx0;
    const unsigned short* al1 = Alo + (size_t)(bm + row1) * K + cx1;
    const unsigned short* bh0 = Bhi + (size_t)(bn + row0) * K + cx0;
    const unsigned short* bh1 = Bhi + (size_t)(bn + row1) * K + cx1;
    const unsigned short* bl0 = Blo + (size_t)(bn + row0) * K + cx0;
    const unsigned short* bl1 = Blo + (size_t)(bn + row1) * K + cx1;

    f32x4 acc[4][4];
#pragma unroll
    for (int i = 0; i < 4; ++i)
#pragma unroll
        for (int j = 0; j < 4; ++j) acc[i][j] = (f32x4){0.f, 0.f, 0.f, 0.f};

    for (int k0 = 0; k0 < K; k0 += 32) {
        GLOAD16(ah0 + k0, &Ah[wr * 32]);
        GLOAD16(ah1 + k0, &Ah[(wr + 16) * 32]);
        if constexpr (ALO) {
            GLOAD16(al0 + k0, &Al[wr * 32]);
            GLOAD16(al1 + k0, &Al[(wr + 16) * 32]);
        }
        GLOAD16(bh0 + k0, &Bh[wr * 32]);
        GLOAD16(bh1 + k0, &Bh[(wr + 16) * 32]);
        GLOAD16(bl0 + k0, &Bl[wr * 32]);
        GLOAD16(bl1 + k0, &Bl[(wr + 16) * 32]);
        __syncthreads();

        s16x8 ah[4], al[4], bhf[4], blf[4];
#pragma unroll
        for (int m = 0; m < 4; ++m) {
            int row = wm * 64 + m * 16 + r15;
            int off = row * 32 + ((q ^ ((row >> 1) & 3)) << 3);
            ah[m] = *(const s16x8*)&Ah[off];
            if constexpr (ALO) al[m] = *(const s16x8*)&Al[off];
        }
#pragma unroll
        for (int n = 0; n < 4; ++n) {
            int row = wn * 64 + n * 16 + r15;
            int off = row * 32 + ((q ^ ((row >> 1) & 3)) << 3);
            bhf[n] = *(const s16x8*)&Bh[off];
            blf[n] = *(const s16x8*)&Bl[off];
        }
#pragma unroll
        for (int m = 0; m < 4; ++m)
#pragma unroll
            for (int n = 0; n < 4; ++n) {
                bf16x8 a_h = __builtin_bit_cast(bf16x8, ah[m]);
                bf16x8 b_h = __builtin_bit_cast(bf16x8, bhf[n]);
                bf16x8 b_l = __builtin_bit_cast(bf16x8, blf[n]);
                acc[m][n] = __builtin_amdgcn_mfma_f32_16x16x32_bf16(a_h, b_h, acc[m][n], 0, 0, 0);
                acc[m][n] = __builtin_amdgcn_mfma_f32_16x16x32_bf16(a_h, b_l, acc[m][n], 0, 0, 0);
                if constexpr (ALO) {
                    bf16x8 a_l = __builtin_bit_cast(bf16x8, al[m]);
                    acc[m][n] = __builtin_amdgcn_mfma_f32_16x16x32_bf16(a_l, b_h, acc[m][n], 0, 0, 0);
                }
            }
        __syncthreads();
    }

#pragma unroll
    for (int n = 0; n < 4; ++n) {
        int col = bn + wn * 64 + n * 16 + r15;
        float bb = bias[col];
#pragma unroll
        for (int m = 0; m < 4; ++m) {
            int r0 = bm + wm * 64 + m * 16 + q * 4;
#pragma unroll
            for (int i = 0; i < 4; ++i) {
                float v = acc[m][n][i] + bb;
                if (ACT == 1) v = 0.5f * v * (1.0f + erff(v * 0.70710678118654752f));
                size_t off = (size_t)(r0 + i) * N + col;
                if constexpr (OMODE == 0) C[off] = v;
                else C[off] += v;
            }
        }
    }
}

// ---------------------------------------------------------------------------
// Fused MLP: out += GeLU(x*W1^T + b1) * W2^T + b2, per 128-row m-tile.
// x pre-split hi/lo [M,256]; W1 [1024,256] hi/lo; W2 [256,1024] hi/lo.
// h (hi bf16) lives only in LDS. 8 h-chunks of 128.
__global__ __launch_bounds__(256) void mlp_fused(const unsigned short* __restrict__ xhp,
                                                 const unsigned short* __restrict__ xlp,
                                                 const unsigned short* __restrict__ w1h,
                                                 const unsigned short* __restrict__ w1l,
                                                 const float* __restrict__ b1,
                                                 const unsigned short* __restrict__ w2h,
                                                 const unsigned short* __restrict__ w2l,
                                                 const float* __restrict__ b2,
                                                 float* __restrict__ outb) {
    // phase-aliased LDS: p1 {Xh,Xl | W1h,W1l}, p2 {W2h | W2l}; Hs separate.
    __shared__ unsigned short u0[8192];    // p1: Xh[0:4096) Xl[4096:8192); p2: W2h[256][32]
    __shared__ unsigned short u1[8192];    // p1: W1h, W1l;                 p2: W2l
    __shared__ unsigned short Hs[16384];   // h [128 rows][128 k], chunk^(row&7) swizzle
    const int tid = threadIdx.x;
    const int bm = blockIdx.x * 128;
    const int lane = tid & 63, wid = tid >> 6;
    const int wm = wid & 1, wn = wid >> 1;
    const int qh = lane >> 4, r15 = lane & 15;
    const int rl = lane >> 2, cc = lane & 3;
    const int wr = wid * 32;

    unsigned short* Xh = u0;      unsigned short* Xl = u0 + 4096;
    unsigned short* W1h = u1;     unsigned short* W1l = u1 + 4096;
    unsigned short* W2h = u0;     unsigned short* W2l = u1;

    // phase-1 staging sources (K=256)
    const int row0 = wr + rl, row1 = wr + 16 + rl;
    const int cx0 = (cc ^ ((row0 >> 1) & 3)) << 3;
    const int cx1 = (cc ^ ((row1 >> 1) & 3)) << 3;
    const unsigned short* xh0 = xhp + (size_t)(bm + row0) * 256 + cx0;
    const unsigned short* xh1 = xhp + (size_t)(bm + row1) * 256 + cx1;
    const unsigned short* xl0 = xlp + (size_t)(bm + row0) * 256 + cx0;
    const unsigned short* xl1 = xlp + (size_t)(bm + row1) * 256 + cx1;
    const unsigned short* w1h0 = w1h + (size_t)row0 * 256 + cx0;
    const unsigned short* w1h1 = w1h + (size_t)row1 * 256 + cx1;
    const unsigned short* w1l0 = w1l + (size_t)row0 * 256 + cx0;
    const unsigned short* w1l1 = w1l + (size_t)row1 * 256 + cx1;

    // phase-2 staging sources: rows = out-cols (256), stride 1024
    const unsigned short* w2hs[4];
    const unsigned short* w2ls[4];
#pragma unroll
    for (int g = 0; g < 4; ++g) {
        int rowg = wid * 64 + g * 16 + rl;
        int cxg = (cc ^ ((rowg >> 1) & 3)) << 3;
        w2hs[g] = w2h + (size_t)rowg * 1024 + cxg;
        w2ls[g] = w2l + (size_t)rowg * 1024 + cxg;
    }

    f32x4 oacc[4][8];
#pragma unroll
    for (int m = 0; m < 4; ++m)
#pragma unroll
        for (int n = 0; n < 8; ++n) oacc[m][n] = (f32x4){0.f, 0.f, 0.f, 0.f};

    for (int j = 0; j < 8; ++j) {
        const size_t w1off = (size_t)j * 32768;     // j*128 rows * 256
        // ---- phase 1: h = x * w1_j^T
        f32x4 hacc[4][4];
#pragma unroll
        for (int m = 0; m < 4; ++m)
#pragma unroll
            for (int n = 0; n < 4; ++n) hacc[m][n] = (f32x4){0.f, 0.f, 0.f, 0.f};

        for (int k0 = 0; k0 < 256; k0 += 32) {
            GLOAD16(xh0 + k0, &Xh[wr * 32]);
            GLOAD16(xh1 + k0, &Xh[(wr + 16) * 32]);
            GLOAD16(xl0 + k0, &Xl[wr * 32]);
            GLOAD16(xl1 + k0, &Xl[(wr + 16) * 32]);
            GLOAD16(w1h0 + w1off + k0, &W1h[wr * 32]);
            GLOAD16(w1h1 + w1off + k0, &W1h[(wr + 16) * 32]);
            GLOAD16(w1l0 + w1off + k0, &W1l[wr * 32]);
            GLOAD16(w1l1 + w1off + k0, &W1l[(wr + 16) * 32]);
            __syncthreads();

            s16x8 ah[4], al[4], bhf[4], blf[4];
#pragma unroll
            for (int m = 0; m < 4; ++m) {
                int row = wm * 64 + m * 16 + r15;
                int off = row * 32 + ((qh ^ ((row >> 1) & 3)) << 3);
                ah[m] = *(const s16x8*)&Xh[off];
                al[m] = *(const s16x8*)&Xl[off];
            }
#pragma unroll
            for (int n = 0; n < 4; ++n) {
                int row = wn * 64 + n * 16 + r15;
                int off = row * 32 + ((qh ^ ((row >> 1) & 3)) << 3);
                bhf[n] = *(const s16x8*)&W1h[off];
                blf[n] = *(const s16x8*)&W1l[off];
            }
#pragma unroll
            for (int m = 0; m < 4; ++m)
#pragma unroll
                for (int n = 0; n < 4; ++n) {
                    bf16x8 a_h = __builtin_bit_cast(bf16x8, ah[m]);
                    bf16x8 a_l = __builtin_bit_cast(bf16x8, al[m]);
                    bf16x8 b_h = __builtin_bit_cast(bf16x8, bhf[n]);
                    bf16x8 b_l = __builtin_bit_cast(bf16x8, blf[n]);
                    hacc[m][n] = __builtin_amdgcn_mfma_f32_16x16x32_bf16(a_h, b_h, hacc[m][n], 0, 0, 0);
                    hacc[m][n] = __builtin_amdgcn_mfma_f32_16x16x32_bf16(a_h, b_l, hacc[m][n], 0, 0, 0);
                    hacc[m][n] = __builtin_amdgcn_mfma_f32_16x16x32_bf16(a_l, b_h, hacc[m][n], 0, 0, 0);
                }
            __syncthreads();
        }

        // ---- GeLU + write h (hi bf16) to swizzled LDS
#pragma unroll
        for (int n = 0; n < 4; ++n) {
            int col = wn * 64 + n * 16 + r15;
            float bb = b1[j * 128 + col];
            int chi = col >> 3, clo = col & 7;
#pragma unroll
            for (int m = 0; m < 4; ++m) {
                int rbase = wm * 64 + m * 16 + qh * 4;
#pragma unroll
                for (int i = 0; i < 4; ++i) {
                    int row = rbase + i;
                    float v = hacc[m][n][i] + bb;
                    v = 0.5f * v * (1.0f + erff(v * 0.70710678118654752f));
                    Hs[row * 128 + ((chi ^ (row & 7)) << 3) + clo] =
                        (unsigned short)bf16_rn(v);
                }
            }
        }
        __syncthreads();

        // ---- phase 2: oacc += h * w2_j^T  (k = 128, 4 steps)
        for (int kk = 0; kk < 4; ++kk) {
#pragma unroll
            for (int g = 0; g < 4; ++g) {
                GLOAD16(w2hs[g] + j * 128 + kk * 32, &W2h[(wid * 64 + g * 16) * 32]);
                GLOAD16(w2ls[g] + j * 128 + kk * 32, &W2l[(wid * 64 + g * 16) * 32]);
            }
            __syncthreads();

            s16x8 pa[4], pbh[8], pbl[8];
#pragma unroll
            for (int m = 0; m < 4; ++m) {
                int row = wm * 64 + m * 16 + r15;
                int c = kk * 4 + qh;
                pa[m] = *(const s16x8*)&Hs[row * 128 + ((c ^ (row & 7)) << 3)];
            }
#pragma unroll
            for (int n = 0; n < 8; ++n) {
                int row = wn * 128 + n * 16 + r15;
                int off = row * 32 + ((qh ^ ((row >> 1) & 3)) << 3);
                pbh[n] = *(const s16x8*)&W2h[off];
                pbl[n] = *(const s16x8*)&W2l[off];
            }
#pragma unroll
            for (int m = 0; m < 4; ++m)
#pragma unroll
                for (int n = 0; n < 8; ++n) {
                    bf16x8 a_h = __builtin_bit_cast(bf16x8, pa[m]);
                    bf16x8 b_h = __builtin_bit_cast(bf16x8, pbh[n]);
                    bf16x8 b_l = __builtin_bit_cast(bf16x8, pbl[n]);
                    oacc[m][n] = __builtin_amdgcn_mfma_f32_16x16x32_bf16(a_h, b_h, oacc[m][n], 0, 0, 0);
                    oacc[m][n] = __builtin_amdgcn_mfma_f32_16x16x32_bf16(a_h, b_l, oacc[m][n], 0, 0, 0);
                }
            __syncthreads();
        }
    }

    // ---- epilogue: out += oacc + b2
#pragma unroll
    for (int n = 0; n < 8; ++n) {
        int col = wn * 128 + n * 16 + r15;
        float bb = b2[col];
#pragma unroll
        for (int m = 0; m < 4; ++m) {
            int r0 = bm + wm * 64 + m * 16 + qh * 4;
#pragma unroll
            for (int i = 0; i < 4; ++i)
                outb[(size_t)(r0 + i) * 256 + col] += oacc[m][n][i] + bb;
        }
    }
}

// ---------------------------------------------------------------------------
// QKV GEMM: A pre-split (gload), COMPACT block-diagonal B (hi only, reg-staged),
// split bf16 output. M=MROWS, N=768, K=256.
__global__ __launch_bounds__(256) void gemm_qkv2(const unsigned short* __restrict__ Ahi,
                                                 const unsigned short* __restrict__ Alo,
                                                 const unsigned short* __restrict__ Bc,
                                                 const float* __restrict__ bias,
                                                 unsigned short* __restrict__ Chi,
                                                 unsigned short* __restrict__ Clo) {
    __shared__ unsigned short Ah[4096], Al[4096], Bh[4096];
    const int tid = threadIdx.x;
    const int bm = blockIdx.y * 128, bn = blockIdx.x * 128;
    const int lane = tid & 63, wid = tid >> 6;
    const int wm = wid & 1, wn = wid >> 1;
    const int q = lane >> 4, r15 = lane & 15;
    const int rl = lane >> 2, cc = lane & 3;
    const int wr = wid * 32;
    const int K = 256, N = 768;

    const int row0 = wr + rl, row1 = wr + 16 + rl;
    const int cx0 = (cc ^ ((row0 >> 1) & 3)) << 3;
    const int cx1 = (cc ^ ((row1 >> 1) & 3)) << 3;
    const unsigned short* ah0 = Ahi + (size_t)(bm + row0) * K + cx0;
    const unsigned short* ah1 = Ahi + (size_t)(bm + row1) * K + cx1;
    const unsigned short* al0 = Alo + (size_t)(bm + row0) * K + cx0;
    const unsigned short* al1 = Alo + (size_t)(bm + row1) * K + cx1;

    const int srow = tid >> 2, sc = tid & 3;
    const int j0 = bn + srow, j1 = bn + srow + 64;
    const int c0 = (j0 >> 5) & 7, c1 = (j1 >> 5) & 7;
    const unsigned short* bc0 = Bc + (size_t)j0 * 32 + sc * 8;
    const unsigned short* bc1 = Bc + (size_t)j1 * 32 + sc * 8;
    const int soff0 = swz(srow, sc), soff1 = swz(srow + 64, sc);

    f32x4 acc[4][4];
#pragma unroll
    for (int i = 0; i < 4; ++i)
#pragma unroll
        for (int j = 0; j < 4; ++j) acc[i][j] = (f32x4){0.f, 0.f, 0.f, 0.f};

    const s16x8 bz = (s16x8){0, 0, 0, 0, 0, 0, 0, 0};
    for (int k0 = 0; k0 < K; k0 += 32) {
        const int kc = k0 >> 5;
        GLOAD16(ah0 + k0, &Ah[wr * 32]);
        GLOAD16(ah1 + k0, &Ah[(wr + 16) * 32]);
        GLOAD16(al0 + k0, &Al[wr * 32]);
        GLOAD16(al1 + k0, &Al[(wr + 16) * 32]);
        *(s16x8*)&Bh[soff0] = (c0 == kc) ? *(const s16x8*)bc0 : bz;
        *(s16x8*)&Bh[soff1] = (c1 == kc) ? *(const s16x8*)bc1 : bz;
        __syncthreads();

        s16x8 ah[4], al[4], bhf[4];
#pragma unroll
        for (int m = 0; m < 4; ++m) {
            int row = wm * 64 + m * 16 + r15;
            int off = row * 32 + ((q ^ ((row >> 1) & 3)) << 3);
            ah[m] = *(const s16x8*)&Ah[off];
            al[m] = *(const s16x8*)&Al[off];
        }
#pragma unroll
        for (int n = 0; n < 4; ++n) {
            int row = wn * 64 + n * 16 + r15;
            int off = row * 32 + ((q ^ ((row >> 1) & 3)) << 3);
            bhf[n] = *(const s16x8*)&Bh[off];
        }
#pragma unroll
        for (int m = 0; m < 4; ++m)
#pragma unroll
            for (int n = 0; n < 4; ++n) {
                bf16x8 a_h = __builtin_bit_cast(bf16x8, ah[m]);
                bf16x8 a_l = __builtin_bit_cast(bf16x8, al[m]);
                bf16x8 b_h = __builtin_bit_cast(bf16x8, bhf[n]);
                acc[m][n] = __builtin_amdgcn_mfma_f32_16x16x32_bf16(a_h, b_h, acc[m][n], 0, 0, 0);
                acc[m][n] = __builtin_amdgcn_mfma_f32_16x16x32_bf16(a_l, b_h, acc[m][n], 0, 0, 0);
            }
        __syncthreads();
    }

#pragma unroll
    for (int n = 0; n < 4; ++n) {
        int col = bn + wn * 64 + n * 16 + r15;
        float bb = bias[col];
#pragma unroll
        for (int m = 0; m < 4; ++m) {
            int r0 = bm + wm * 64 + m * 16 + q * 4;
#pragma unroll
            for (int i = 0; i < 4; ++i) {
                float v = acc[m][n][i] + bb;
                size_t off = (size_t)(r0 + i) * N + col;
                unsigned short hh, ll; split2(v, hh, ll);
                Chi[off] = hh; Clo[off] = ll;
            }
        }
    }
}

// ---------------------------------------------------------------------------
// Patch-embed GEMM (reg-staged, one-time). M=25088, N=256, K=768.
__global__ __launch_bounds__(256) void patch_mfma(const float* __restrict__ images,
                                                  const unsigned short* __restrict__ Bhi,
                                                  const unsigned short* __restrict__ Blo,
                                                  const float* __restrict__ b_map,
                                                  const float* __restrict__ pe,
                                                  float* __restrict__ out) {
    __shared__ unsigned short Ah[4096], Al[4096], Bh[4096], Bl[4096];
    const int tid = threadIdx.x;
    const int bm = blockIdx.y * 128, bn = blockIdx.x * 128;
    const int lane = tid & 63, wid = tid >> 6;
    const int wm = wid & 1, wn = wid >> 1;
    const int q = lane >> 4, r15 = lane & 15;
    const int srow = tid >> 2, sc = tid & 3;

    const float* ibase[2];
    {
        int rows[2] = {bm + srow, bm + srow + 64};
#pragma unroll
        for (int t = 0; t < 2; ++t) {
            int n = rows[t] / 196, p = rows[t] % 196;
            ibase[t] = images + (size_t)n * 150528 + (size_t)(p / 14) * 3584 + (p % 14) * 16;
        }
    }
    const int soff0 = swz(srow, sc), soff1 = swz(srow + 64, sc);
    const unsigned short* bh0 = Bhi + (size_t)(bn + srow) * 768 + sc * 8;
    const unsigned short* bl0 = Blo + (size_t)(bn + srow) * 768 + sc * 8;
    const unsigned short* bh1 = Bhi + (size_t)(bn + srow + 64) * 768 + sc * 8;
    const unsigned short* bl1 = Blo + (size_t)(bn + srow + 64) * 768 + sc * 8;

    f32x4 acc[4][4];
#pragma unroll
    for (int i = 0; i < 4; ++i)
#pragma unroll
        for (int j = 0; j < 4; ++j) acc[i][j] = (f32x4){0.f, 0.f, 0.f, 0.f};

    for (int k0 = 0; k0 < 768; k0 += 32) {
        int k = k0 + sc * 8;
        int aoff = (k >> 8) * 50176 + (((k >> 4) & 15)) * 224 + (k & 15);
        {
            float4 v0 = *(const float4*)(ibase[0] + aoff);
            float4 v1 = *(const float4*)(ibase[0] + aoff + 4);
            float vv[8] = {v0.x, v0.y, v0.z, v0.w, v1.x, v1.y, v1.z, v1.w};
            s16x8 hv, lv;
#pragma unroll
            for (int j = 0; j < 8; ++j) {
                unsigned short h, l; split2(vv[j], h, l);
                hv[j] = (short)h; lv[j] = (short)l;
            }
            *(s16x8*)&Ah[soff0] = hv; *(s16x8*)&Al[soff0] = lv;
            v0 = *(const float4*)(ibase[1] + aoff);
            v1 = *(const float4*)(ibase[1] + aoff + 4);
            float ww[8] = {v0.x, v0.y, v0.z, v0.w, v1.x, v1.y, v1.z, v1.w};
#pragma unroll
            for (int j = 0; j < 8; ++j) {
                unsigned short h, l; split2(ww[j], h, l);
                hv[j] = (short)h; lv[j] = (short)l;
            }
            *(s16x8*)&Ah[soff1] = hv; *(s16x8*)&Al[soff1] = lv;
        }
        *(s16x8*)&Bh[soff0] = *(const s16x8*)(bh0 + k0);
        *(s16x8*)&Bl[soff0] = *(const s16x8*)(bl0 + k0);
        *(s16x8*)&Bh[soff1] = *(const s16x8*)(bh1 + k0);
        *(s16x8*)&Bl[soff1] = *(const s16x8*)(bl1 + k0);
        __syncthreads();

        s16x8 ah[4], al[4], bhf[4], blf[4];
#pragma unroll
        for (int m = 0; m < 4; ++m) {
            int row = wm * 64 + m * 16 + r15;
            int off = row * 32 + ((q ^ ((row >> 1) & 3)) << 3);
            ah[m] = *(const s16x8*)&Ah[off];
            al[m] = *(const s16x8*)&Al[off];
        }
#pragma unroll
        for (int n = 0; n < 4; ++n) {
            int row = wn * 64 + n * 16 + r15;
            int off = row * 32 + ((q ^ ((row >> 1) & 3)) << 3);
            bhf[n] = *(const s16x8*)&Bh[off];
            blf[n] = *(const s16x8*)&Bl[off];
        }
#pragma unroll
        for (int m = 0; m < 4; ++m)
#pragma unroll
            for (int n = 0; n < 4; ++n) {
                bf16x8 a_h = __builtin_bit_cast(bf16x8, ah[m]);
                bf16x8 a_l = __builtin_bit_cast(bf16x8, al[m]);
                bf16x8 b_h = __builtin_bit_cast(bf16x8, bhf[n]);
                bf16x8 b_l = __builtin_bit_cast(bf16x8, blf[n]);
                acc[m][n] = __builtin_amdgcn_mfma_f32_16x16x32_bf16(a_h, b_h, acc[m][n], 0, 0, 0);
                acc[m][n] = __builtin_amdgcn_mfma_f32_16x16x32_bf16(a_h, b_l, acc[m][n], 0, 0, 0);
                acc[m][n] = __builtin_amdgcn_mfma_f32_16x16x32_bf16(a_l, b_h, acc[m][n], 0, 0, 0);
            }
        __syncthreads();
    }

#pragma unroll
    for (int n = 0; n < 4; ++n) {
        int col = bn + wn * 64 + n * 16 + r15;
        float bb = b_map[col];
#pragma unroll
        for (int m = 0; m < 4; ++m) {
            int row0 = bm + wm * 64 + m * 16 + q * 4;
#pragma unroll
            for (int i = 0; i < 4; ++i) {
                int rowg = row0 + i;
                int n_img = rowg / 196;
                int p = rowg - n_img * 196;
                out[((size_t)n_img * SEQ + 1 + p) * DIM + col] =
                    acc[m][n][i] + bb + pe[(1 + p) * DIM + col];
            }
        }
    }
}

// ---------------------------------------------------------------------------
// MFMA attention reading pre-split qkv; writes split bf16 O.
__global__ __launch_bounds__(256) void attn_mfma2(const unsigned short* __restrict__ qkvh,
                                                  const unsigned short* __restrict__ qkvl,
                                                  unsigned short* __restrict__ oh,
                                                  unsigned short* __restrict__ ol) {
    __shared__ unsigned short Kh[208 * 40];      // K[s][d], rows >=197 zero
    __shared__ unsigned short Vt[32 * 232];      // V^T[d][t], cols >=197 zero
    __shared__ unsigned short Pb[4][16 * 232];   // per-wave P[qr][t]
    const int tid = threadIdx.x;
    const int lane = tid & 63, wid = tid >> 6;
    const int qh = lane >> 4, qr = lane & 15;
    const int n = blockIdx.x >> 3, h = blockIdx.x & 7;
    const size_t rowbase = (size_t)n * SEQ;
    const float scale = 0.17677669529663687f;    // 1/sqrt(32)

    for (int i = tid; i < 208 * 40 / 2; i += 256) ((uint32_t*)Kh)[i] = 0;
    for (int i = tid; i < 32 * 232 / 2; i += 256) ((uint32_t*)Vt)[i] = 0;
    for (int i = tid; i < 4 * 16 * 232 / 2; i += 256) ((uint32_t*)&Pb[0][0])[i] = 0;
    __syncthreads();

    for (int e = tid; e < SEQ * 4; e += 256) {
        int s = e >> 2, c = e & 3;
        *(s16x8*)&Kh[s * 40 + c * 8] =
            *(const s16x8*)(qkvh + (rowbase + s) * 768 + 256 + h * 32 + c * 8);
    }
    for (int e = tid; e < SEQ * 32; e += 256) {
        int s = e >> 5, d = e & 31;
        Vt[d * 232 + s] = qkvh[(rowbase + s) * 768 + 512 + h * 32 + d];
    }
    __syncthreads();

    unsigned short* Pw = Pb[wid];
    for (int st = wid; st < 13; st += 4) {
        int srow = st * 16 + qr; if (srow > SEQ - 1) srow = SEQ - 1;
        const size_t qoff = (rowbase + srow) * 768 + h * 32 + qh * 8;
        bf16x8 qH = *(const bf16x8*)(qkvh + qoff);
        bf16x8 qL = *(const bf16x8*)(qkvl + qoff);

        f32x4 sacc[13];
#pragma unroll
        for (int tt = 0; tt < 13; ++tt) sacc[tt] = (f32x4){0.f, 0.f, 0.f, 0.f};
#pragma unroll
        for (int tt = 0; tt < 13; ++tt) {
            bf16x8 kf = *(const bf16x8*)&Kh[(tt * 16 + qr) * 40 + qh * 8];
            sacc[tt] = __builtin_amdgcn_mfma_f32_16x16x32_bf16(kf, qH, sacc[tt], 0, 0, 0);
            sacc[tt] = __builtin_amdgcn_mfma_f32_16x16x32_bf16(kf, qL, sacc[tt], 0, 0, 0);
        }
#pragma unroll
        for (int i = 0; i < 4; ++i)
            if (192 + 4 * qh + i > SEQ - 1) sacc[12][i] = -1e4f;
        float mx = -1e4f;
#pragma unroll
        for (int tt = 0; tt < 13; ++tt)
#pragma unroll
            for (int i = 0; i < 4; ++i) mx = fmaxf(mx, sacc[tt][i]);
        mx = fmaxf(mx, __shfl_xor(mx, 16, 64));
        mx = fmaxf(mx, __shfl_xor(mx, 32, 64));
        float sum = 0.f;
#pragma unroll
        for (int tt = 0; tt < 13; ++tt)
#pragma unroll
            for (int i = 0; i < 4; ++i) {
                float p = __expf((sacc[tt][i] - mx) * scale);
                sacc[tt][i] = p; sum += p;
            }
        sum += __shfl_xor(sum, 16, 64);
        sum += __shfl_xor(sum, 32, 64);
        float inv = 1.0f / sum;
#pragma unroll
        for (int tt = 0; tt < 13; ++tt)
#pragma unroll
            for (int i = 0; i < 4; ++i)
                Pw[qr * 232 + tt * 16 + 4 * qh + i] = (unsigned short)bf16_rn(sacc[tt][i]);
#pragma unroll
        for (int i = 0; i < 4; ++i)
            Pw[qr * 232 + 208 + 4 * qh + i] = 0;

        f32x4 oacc[2];
        oacc[0] = (f32x4){0.f, 0.f, 0.f, 0.f};
        oacc[1] = (f32x4){0.f, 0.f, 0.f, 0.f};
#pragma unroll
        for (int kt = 0; kt < 7; ++kt) {
            bf16x8 pf = *(const bf16x8*)&Pw[qr * 232 + kt * 32 + qh * 8];
            bf16x8 v0 = *(const bf16x8*)&Vt[qr * 232 + kt * 32 + qh * 8];
            bf16x8 v1 = *(const bf16x8*)&Vt[(16 + qr) * 232 + kt * 32 + qh * 8];
            oacc[0] = __builtin_amdgcn_mfma_f32_16x16x32_bf16(v0, pf, oacc[0], 0, 0, 0);
            oacc[1] = __builtin_amdgcn_mfma_f32_16x16x32_bf16(v1, pf, oacc[1], 0, 0, 0);
        }
        if (st * 16 + qr < SEQ) {
            size_t obase = (rowbase + st * 16 + qr) * DIM + h * 32;
#pragma unroll
            for (int dt = 0; dt < 2; ++dt)
#pragma unroll
                for (int i = 0; i < 4; ++i) {
                    unsigned short hh, ll;
                    split2(oacc[dt][i] * inv, hh, ll);
                    oh[obase + dt * 16 + 4 * qh + i] = hh;
                    ol[obase + dt * 16 + 4 * qh + i] = ll;
                }
        }
    }
}

// ---------------------------------------------------------------------------
// LayerNorm -> split bf16 output. One block per row.
__global__ __launch_bounds__(256) void ln_split(const float* __restrict__ x,
                                                unsigned short* __restrict__ yh,
                                                unsigned short* __restrict__ yl,
                                                const float* __restrict__ g,
                                                const float* __restrict__ b) {
    int row = blockIdx.x, tid = threadIdx.x;
    float v = x[(size_t)row * DIM + tid];
    float s = v;
#pragma unroll
    for (int off = 32; off; off >>= 1) s += __shfl_down(s, off, 64);
    __shared__ float red[4];
    if ((tid & 63) == 0) red[tid >> 6] = s;
    __syncthreads();
    float mu = (red[0] + red[1] + red[2] + red[3]) * (1.0f / 256.0f);
    float d = v - mu;
    float s2 = d * d;
#pragma unroll
    for (int off = 32; off; off >>= 1) s2 += __shfl_down(s2, off, 64);
    __shared__ float red2[4];
    if ((tid & 63) == 0) red2[tid >> 6] = s2;
    __syncthreads();
    float var = (red2[0] + red2[1] + red2[2] + red2[3]) * (1.0f / 256.0f);
    float inv_std = 1.0f / sqrtf(var + 1e-5f);
    float y = d * inv_std * g[tid] + b[tid];
    unsigned short hh, ll; split2(y, hh, ll);
    size_t off = (size_t)row * DIM + tid;
    yh[off] = hh; yl[off] = ll;
}

// ---------------------------------------------------------------------------
__global__ __launch_bounds__(256) void head_kernel(const float* __restrict__ xin,
                                                   const float* __restrict__ w,
                                                   const float* __restrict__ bias,
                                                   float* __restrict__ res) {
    int n = blockIdx.x, tid = threadIdx.x;
    __shared__ float xs[256];
    xs[tid] = xin[(size_t)n * SEQ * DIM + tid];
    __syncthreads();
    float lg[4];
#pragma unroll
    for (int u = 0; u < 4; ++u) {
        int j = u * 256 + tid;
        float acc = -1e30f;
        if (j < 1000) {
            acc = bias[j];
            for (int kk = 0; kk < 256; kk += 4) {
                float4 wv = *reinterpret_cast<const float4*>(&w[(size_t)j * 256 + kk]);
                acc += xs[kk] * wv.x + xs[kk + 1] * wv.y + xs[kk + 2] * wv.z + xs[kk + 3] * wv.w;
            }
        }
        lg[u] = acc;
    }
    float mx = fmaxf(fmaxf(lg[0], lg[1]), fmaxf(lg[2], lg[3]));
#pragma unroll
    for (int off = 32; off; off >>= 1) mx = fmaxf(mx, __shfl_down(mx, off, 64));
    __shared__ float redm[4];
    if ((tid & 63) == 0) redm[tid >> 6] = mx;
    __syncthreads();
    mx = fmaxf(fmaxf(redm[0], redm[1]), fmaxf(redm[2], redm[3]));
    float e[4], ssum = 0.f;
#pragma unroll
    for (int u = 0; u < 4; ++u) {
        int j = u * 256 + tid;
        e[u] = (j < 1000) ? expf(lg[u] - mx) : 0.f;
        ssum += e[u];
    }
#pragma unroll
    for (int off = 32; off; off >>= 1) ssum += __shfl_down(ssum, off, 64);
    __shared__ float reds[4];
    if ((tid & 63) == 0) reds[tid >> 6] = ssum;
    __syncthreads();
    float inv = 1.0f / (reds[0] + reds[1] + reds[2] + reds[3]);
#pragma unroll
    for (int u = 0; u < 4; ++u) {
        int j = u * 256 + tid;
        if (j < 1000) res[(size_t)n * 1000 + j] = e[u] * inv;
    }
}

// ---------------------------------------------------------------------------
extern "C" void kernel_launch(void* const* d_in, const int* in_sizes, int n_in,
                              void* d_out, int out_size, void* d_ws, size_t ws_size,
                              hipStream_t stream) {
    const float* images  = (const float*)d_in[0];
    const float* w_map   = (const float*)d_in[1];
    const float* b_map   = (const float*)d_in[2];
    const float* cls_tok = (const float*)d_in[3];
    const float* norm1_g = (const float*)d_in[4];
    const float* norm1_b = (const float*)d_in[5];
    const float* wq      = (const float*)d_in[6];
    const float* bq      = (const float*)d_in[7];
    const float* wk      = (const float*)d_in[8];
    const float* bk      = (const float*)d_in[9];
    const float* wv      = (const float*)d_in[10];
    const float* bv      = (const float*)d_in[11];
    const float* w_last  = (const float*)d_in[12];
    const float* b_last  = (const float*)d_in[13];
    const float* norm2_g = (const float*)d_in[14];
    const float* norm2_b = (const float*)d_in[15];
    const float* w_mlp1  = (const float*)d_in[16];
    const float* b_mlp1  = (const float*)d_in[17];
    const float* w_mlp2  = (const float*)d_in[18];
    const float* b_mlp2  = (const float*)d_in[19];
    const float* w_out   = (const float*)d_in[20];
    const float* b_out   = (const float*)d_in[21];

    float* wsf = (float*)d_ws;
    const size_t SZ = (size_t)MROWS * DIM;   // 6,455,296 floats
    float* outb = wsf;                               // residual [M,256] f32
    unsigned short* xh  = (unsigned short*)(wsf + SZ);       // LN out hi
    unsigned short* xl  = xh + SZ;                           // LN out lo
    unsigned short* qkvh = (unsigned short*)(wsf + 2 * SZ);  // [M,768] hi
    unsigned short* qkvl = qkvh + 3 * SZ;                    // [M,768] lo
    unsigned short* oh  = (unsigned short*)(wsf + 5 * SZ);   // attn out hi
    unsigned short* olo = oh + SZ;                           // attn out lo
    float* peb  = wsf + 6 * SZ;                              // 50432 floats

    // weight buffers: identical layout to R3/R4 (proven within ws_size)
    const size_t W_MAP  = 0;                 // 196608
    const size_t W_LAST = 196608;            // 4 * 65536
    const size_t W_MLP1 = 458752;            // 4 * 262144
    const size_t W_MLP2 = 1507328;           // 4 * 262144
    const size_t W_TOTAL = 2555904;
    unsigned short* whi = (unsigned short*)(wsf + 6 * SZ + 50432);
    unsigned short* wlo = whi + W_TOTAL;
    unsigned short* wqkvc = wlo + W_TOTAL;   // compact [4][768][32] hi bf16
    float* bqkvp = (float*)(wqkvc + 98304);  // [4][768]

    pe_kernel<<<SEQ, 256, 0, stream>>>(peb);
    split_weights<<<768, 256, 0, stream>>>(w_map,  whi + W_MAP,  wlo + W_MAP,  196608);
    split_weights<<<1024, 256, 0, stream>>>(w_last, whi + W_LAST, wlo + W_LAST, 262144);
    split_weights<<<2048, 256, 0, stream>>>(w_mlp1, whi + W_MLP1, wlo + W_MLP1, 1048576);
    split_weights<<<2048, 256, 0, stream>>>(w_mlp2, whi + W_MLP2, wlo + W_MLP2, 1048576);
    pack_qkv_c<<<384, 256, 0, stream>>>(wq, wk, wv, wqkvc);
    pack_qkv_b<<<12, 256, 0, stream>>>(bq, bk, bv, bqkvp);

    embed_cls<<<NB, 256, 0, stream>>>(cls_tok, peb, outb);
    patch_mfma<<<dim3(2, 196), 256, 0, stream>>>(images, whi + W_MAP, wlo + W_MAP,
                                                 b_map, peb, outb);

    for (int l = 0; l < 4; ++l) {
        ln_split<<<MROWS, 256, 0, stream>>>(outb, xh, xl, norm1_g + l * 256, norm1_b + l * 256);
        gemm_qkv2<<<dim3(6, 197), 256, 0, stream>>>(
            xh, xl, wqkvc + (size_t)l * 24576, bqkvp + l * 768, qkvh, qkvl);
        attn_mfma2<<<NB * 8, 256, 0, stream>>>(qkvh, qkvl, oh, olo);
        gemm_as<0, 1, true><<<dim3(2, 197), 256, 0, stream>>>(
            oh, olo, whi + W_LAST + (size_t)l * 65536, wlo + W_LAST + (size_t)l * 65536,
            b_last + l * 256, outb, MROWS, 256, 256);
        ln_split<<<MROWS, 256, 0, stream>>>(outb, xh, xl, norm2_g + l * 256, norm2_b + l * 256);
        mlp_fused<<<197, 256, 0, stream>>>(
            xh, xl, whi + W_MLP1 + (size_t)l * 262144, wlo + W_MLP1 + (size_t)l * 262144,
            b_mlp1 + l * 1024,
            whi + W_MLP2 + (size_t)l * 262144, wlo + W_MLP2 + (size_t)l * 262144,
            b_mlp2 + l * 256, outb);
    }
    head_kernel<<<NB, 256, 0, stream>>>(outb, w_out, b_out, (float*)d_out);
}